// Round 3
// baseline (864.654 us; speedup 1.0000x reference)
//
#include <hip/hip_runtime.h>
#include <cstddef>

typedef short bf16x8 __attribute__((ext_vector_type(8)));   // 8 bf16 in 4 VGPRs
typedef float f32x4  __attribute__((ext_vector_type(4)));

namespace {
constexpr float QSCALE = 0.17677669529663687f;  // 32^-0.5, folded into wq/bq at prep

// ---- workspace layout (bytes) ----
constexpr size_t BQKV_OFF = 0;                         // ushort[576][384]  B_T for qkv, [wh|wl] split
constexpr size_t WOUT_OFF = 576 * 384 * 2;             // ushort[192][384]  B_T for wout
constexpr size_t BQG_OFF  = WOUT_OFF + 192 * 384 * 2;  // float[576] head-grouped qkv bias
constexpr size_t QG_OFF   = BQG_OFF + 576 * 4;         // ushort[11160][72][32]  q  (scaled, bf16)
constexpr size_t KG_OFF   = QG_OFF + (size_t)11160 * 2304 * 2;  // ushort[11160][72][32]  k
constexpr size_t VG_OFF   = KG_OFF + (size_t)11160 * 2304 * 2;  // ushort[11160][32][72]  v^T
// total = VG_OFF + 51,425,280 = 154,867,968 B (~148 MiB) — needs harness scratch >= this.

constexpr int AXS = 392;   // x-split LDS row stride (384 + 8 pad)
}

__device__ __forceinline__ unsigned short f2bf(float f) {
  unsigned int u = __builtin_bit_cast(unsigned int, f);
  return (unsigned short)((u + 0x7FFFu + ((u >> 16) & 1u)) >> 16);   // RNE
}
__device__ __forceinline__ float bf2f(unsigned short h) {
  unsigned int u = ((unsigned int)h) << 16;
  return __builtin_bit_cast(float, u);
}
__device__ __forceinline__ int moffv(int i) { return (i < 4) ? i * 16 : 56; }  // m-tiles {0,16,32,48,56}

// ---------------- prep: weights -> split-bf16 B_T layouts in ws ----------------
__global__ __launch_bounds__(256)
void prep_kernel(const float* __restrict__ wqkv, const float* __restrict__ bqkv,
                 const float* __restrict__ wout, unsigned char* __restrict__ ws) {
  int t = blockIdx.x * 256 + threadIdx.x;
  unsigned short* Bq = (unsigned short*)(ws + BQKV_OFF);
  unsigned short* Bo = (unsigned short*)(ws + WOUT_OFF);
  float* bqg = (float*)(ws + BQG_OFF);
  if (t < 576 * 384) {
    int n = t / 384, kk = t % 384;
    int ksrc = kk % 192, part = kk / 192;
    int h = n / 96, r96 = n % 96, kind = r96 / 32, d = r96 % 32;
    float w = wqkv[(size_t)ksrc * 576 + kind * 192 + h * 32 + d];
    if (kind == 0) w *= QSCALE;
    unsigned short hi = f2bf(w);
    Bq[t] = part ? f2bf(w - bf2f(hi)) : hi;
  } else if (t < 576 * 384 + 192 * 384) {
    int t2 = t - 576 * 384;
    int n = t2 / 384, kk = t2 % 384, ksrc = kk % 192, part = kk / 192;
    float w = wout[(size_t)ksrc * 192 + n];
    unsigned short hi = f2bf(w);
    Bo[t2] = part ? f2bf(w - bf2f(hi)) : hi;
  } else if (t < 576 * 384 + 192 * 384 + 576) {
    int n = t - (576 * 384 + 192 * 384);
    int h = n / 96, r96 = n % 96, kind = r96 / 32, d = r96 % 32;
    float b = bqkv[kind * 192 + h * 32 + d];
    if (kind == 0) b *= QSCALE;
    bqg[n] = b;
  }
}

// Split-GEMM: NM m-tiles x 3 n-tiles over K=192 x 3 term-regions.
// Per K-step: NM A-frag loads reused over 3 n-tiles -> 2 LDS reads per 3 MFMAs,
// live set ~70 VGPR (fits the 4-wave/SIMD 128-VGPR budget).
template<int NM>
__device__ __forceinline__ void split_gemm(const unsigned short* __restrict__ sm,
                                           const unsigned short* __restrict__ Bt,
                                           int ngb, int m0idx, int lanen, int quad,
                                           f32x4 (&acc)[3][NM]) {
  #pragma unroll
  for (int nt = 0; nt < 3; ++nt)
    #pragma unroll
    for (int mi = 0; mi < NM; ++mi)
      acc[nt][mi] = (f32x4){0.f, 0.f, 0.f, 0.f};
  #pragma unroll 1
  for (int reg = 0; reg < 3; ++reg) {          // xh*wh, xh*wl, xl*wh
    const int ab = (reg == 2) ? 192 : 0;
    const int bb = (reg == 1) ? 192 : 0;
    #pragma unroll 2
    for (int s = 0; s < 6; ++s) {
      bf16x8 a[NM];
      #pragma unroll
      for (int mi = 0; mi < NM; ++mi)
        a[mi] = *(const bf16x8*)(sm + (moffv(m0idx + mi) + lanen) * AXS + ab + 32 * s + quad * 8);
      #pragma unroll
      for (int nt = 0; nt < 3; ++nt) {
        bf16x8 bfr = *(const bf16x8*)(Bt + (size_t)((ngb + nt) * 16 + lanen) * 384 + bb + 32 * s + quad * 8);
        #pragma unroll
        for (int mi = 0; mi < NM; ++mi)
          acc[nt][mi] = __builtin_amdgcn_mfma_f32_16x16x32_bf16(a[mi], bfr, acc[nt][mi], 0, 0, 0);
      }
    }
  }
}

template<int NM>
__device__ __forceinline__ void qkv_epi(const f32x4 (&acc)[3][NM], const float* __restrict__ bqg,
                                        unsigned short* __restrict__ qg, unsigned short* __restrict__ kg,
                                        unsigned short* __restrict__ vg,
                                        int w, int ngb, int m0idx, int lanen, int quad) {
  #pragma unroll 1
  for (int nt = 0; nt < 3; ++nt) {
    const int ng = ngb + nt;
    const int h = ng / 6, w6 = (ng % 6) * 16;         // tiles 0-1: q, 2-3: k, 4-5: v
    const float bias = bqg[ng * 16 + lanen];
    const size_t base = (size_t)(w * 6 + h) * 2304;
    #pragma unroll
    for (int mi = 0; mi < NM; ++mi) {
      const int mo = moffv(m0idx + mi);
      if (w6 < 64) {                                  // q or k: row-major [72][32]
        unsigned short* dst = ((w6 < 32) ? qg : kg) + base + (w6 & 31) + lanen;
        #pragma unroll
        for (int r = 0; r < 4; ++r)
          dst[(size_t)(mo + quad * 4 + r) * 32] = f2bf(acc[nt][mi][r] + bias);
      } else {                                        // v^T [32][72]: 4-token pack
        const int d = (w6 - 64) + lanen;
        ushort4 hv;
        hv.x = f2bf(acc[nt][mi][0] + bias); hv.y = f2bf(acc[nt][mi][1] + bias);
        hv.z = f2bf(acc[nt][mi][2] + bias); hv.w = f2bf(acc[nt][mi][3] + bias);
        *(ushort4*)(vg + base + (size_t)d * 72 + mo + quad * 4) = hv;
      }
    }
  }
}

// ---------------- kernel A: QKV GEMM per window -> q/k/v bf16 in ws ----------------
__global__ __launch_bounds__(512)
void qkv_kernel(const float* __restrict__ x, unsigned char* __restrict__ ws) {
  __shared__ unsigned short sm[72 * AXS];             // 56,448 B static -> 2 blocks/CU
  const int w = blockIdx.x, tid = threadIdx.x;
  const int lane = tid & 63, ty = tid >> 6;
  const int lanen = lane & 15, quad = lane >> 4;
  const float* xw = x + (size_t)w * (72 * 192);

  for (int i = tid; i < 3456; i += 512) {             // stage x split (72*192/4 float4 jobs)
    int r = i / 48, c4 = i % 48;
    float4 v = *(const float4*)(xw + r * 192 + c4 * 4);
    unsigned short h0 = f2bf(v.x), h1 = f2bf(v.y), h2 = f2bf(v.z), h3 = f2bf(v.w);
    ushort4 hv; hv.x = h0; hv.y = h1; hv.z = h2; hv.w = h3;
    ushort4 lv;
    lv.x = f2bf(v.x - bf2f(h0)); lv.y = f2bf(v.y - bf2f(h1));
    lv.z = f2bf(v.z - bf2f(h2)); lv.w = f2bf(v.w - bf2f(h3));
    *(ushort4*)(sm + r * AXS + c4 * 4) = hv;
    *(ushort4*)(sm + r * AXS + 192 + c4 * 4) = lv;
  }
  __syncthreads();

  const unsigned short* Bq = (const unsigned short*)(ws + BQKV_OFF);
  const float* bqg = (const float*)(ws + BQG_OFF);
  unsigned short* qg = (unsigned short*)(ws + QG_OFF);
  unsigned short* kg = (unsigned short*)(ws + KG_OFF);
  unsigned short* vg = (unsigned short*)(ws + VG_OFF);

  const int mg = ty >> 2, nq = ty & 3;                // 2 m-groups x 4 wave-columns
  #pragma unroll 1
  for (int it = 0; it < 3; ++it) {
    const int ngb = (nq + 4 * it) * 3;                // n-triple 0..11
    if (mg == 0) {
      f32x4 acc[3][3];
      split_gemm<3>(sm, Bq, ngb, 0, lanen, quad, acc);
      qkv_epi<3>(acc, bqg, qg, kg, vg, w, ngb, 0, lanen, quad);
    } else {
      f32x4 acc[3][2];
      split_gemm<2>(sm, Bq, ngb, 3, lanen, quad, acc);
      qkv_epi<2>(acc, bqg, qg, kg, vg, w, ngb, 3, lanen, quad);
    }
  }
}

// ---------------- kernel B: attention per (window, head) -> po(f32) in out ----------------
__global__ __launch_bounds__(320)
void attn_core(const float* __restrict__ mask, const float* __restrict__ btab,
               const unsigned char* __restrict__ ws, float* __restrict__ out) {
  __shared__ unsigned short V2[32 * 104];             // v^T, tokens padded to 104 (zeros)
  __shared__ unsigned short PB[5 * 16 * 104];         // wave-private P buffers
  const int b = blockIdx.x, w = b / 6, hh = b - w * 6;
  const int tid = threadIdx.x, lane = tid & 63, ty = tid >> 6;
  const int lanen = lane & 15, quad = lane >> 4;
  const int mrow = w % 30, tlat = w % 31, w31 = w / 31;
  const unsigned short* qg = (const unsigned short*)(ws + QG_OFF) + (size_t)b * 2304;
  const unsigned short* kg = (const unsigned short*)(ws + KG_OFF) + (size_t)b * 2304;
  const unsigned short* vg = (const unsigned short*)(ws + VG_OFF) + (size_t)b * 2304;
  const float* maskw = mask + (size_t)mrow * 5184;

  // stage v^T with zero pad (cols 72..103); zero P pads (cols 72..103, each wave its own)
  for (int i = tid; i < 416; i += 320) {              // 32 rows x 13 uint4 chunks
    int r = i / 13, c = i - r * 13;
    uint4 z = make_uint4(0u, 0u, 0u, 0u);
    *(uint4*)(V2 + r * 104 + c * 8) = (c < 9) ? *(const uint4*)(vg + r * 72 + c * 8) : z;
  }
  {
    int wv = tid >> 6, rr = (tid >> 2) & 15, c = tid & 3;   // exactly 320 jobs
    *(uint4*)(PB + wv * 1664 + rr * 104 + 72 + c * 8) = make_uint4(0u, 0u, 0u, 0u);
  }
  __syncthreads();

  const int mo = moffv(ty);                           // one m-strip per wave
  unsigned short* pb = PB + ty * 1664;

  // S = q k^T: q-frag and k-tiles straight from global (L2-hot). Tail rows >=72 of the
  // last k-tile read neighboring ws data; those columns are masked to -1e30 below.
  bf16x8 afr = *(const bf16x8*)(qg + (mo + lanen) * 32 + quad * 8);
  f32x4 s[5];
  #pragma unroll
  for (int t = 0; t < 5; ++t) {
    int no = (t < 4) ? t * 16 : 64;
    bf16x8 bfr = *(const bf16x8*)(kg + (no + lanen) * 32 + quad * 8);
    s[t] = (f32x4){0.f, 0.f, 0.f, 0.f};
    s[t] = __builtin_amdgcn_mfma_f32_16x16x32_bf16(afr, bfr, s[t], 0, 0, 0);
  }
  // bias (arithmetic row map + direct btab gather) + mask + softmax in C-layout regs
  float lg[5][4];
  #pragma unroll
  for (int t = 0; t < 5; ++t) {
    int ct = ((t < 4) ? t * 16 : 64) + lanen;
    #pragma unroll
    for (int r = 0; r < 4; ++r) {
      if (ct < 72) {
        int m = mo + quad * 4 + r;
        unsigned int e = (unsigned)(m % 6); e = e ? 6u - e : 0u;
        unsigned int T = 864u * e + 60u * (unsigned)ct + (unsigned)w31;
        if (T >= 5184u) T -= 5184u;
        unsigned int p1 = T / 72u, p2 = T - 72u * p1;
        unsigned int i1 = p1 / 12u, j1 = p1 - 12u * i1;
        unsigned int i2 = p2 / 12u, j2 = p2 - 12u * i2;
        int rowb = (int)((i1 + 6u * i2) * 23u + j1) - (int)j2 + 11;
        float bv = btab[(size_t)rowb * 186 + tlat * 6 + hh];
        lg[t][r] = s[t][r] + bv + maskw[m * 72 + ct];
      } else lg[t][r] = -1e30f;                       // kill tail garbage (incl. NaN)
    }
  }
  #pragma unroll
  for (int r = 0; r < 4; ++r) {
    float mx = fmaxf(fmaxf(fmaxf(lg[0][r], lg[1][r]), fmaxf(lg[2][r], lg[3][r])), lg[4][r]);
    #pragma unroll
    for (int o = 8; o > 0; o >>= 1) mx = fmaxf(mx, __shfl_xor(mx, o));
    float sum = 0.f;
    #pragma unroll
    for (int t = 0; t < 5; ++t) { lg[t][r] = __expf(lg[t][r] - mx); sum += lg[t][r]; }
    #pragma unroll
    for (int o = 8; o > 0; o >>= 1) sum += __shfl_xor(sum, o);
    float inv = 1.0f / sum;
    #pragma unroll
    for (int t = 0; t < 5; ++t) {
      int ct = ((t < 4) ? t * 16 : 64) + lanen;
      if (ct < 72) pb[(quad * 4 + r) * 104 + ct] = f2bf(lg[t][r] * inv);
    }
  }
  // O = P V  (P cols 72-95 zeroed at stage; v^T tokens 72-95 zeros)
  f32x4 o2[2];
  o2[0] = (f32x4){0.f, 0.f, 0.f, 0.f}; o2[1] = (f32x4){0.f, 0.f, 0.f, 0.f};
  #pragma unroll
  for (int ks = 0; ks < 3; ++ks) {
    bf16x8 pfr = *(const bf16x8*)(pb + lanen * 104 + ks * 32 + quad * 8);
    #pragma unroll
    for (int n2 = 0; n2 < 2; ++n2) {
      bf16x8 vfr = *(const bf16x8*)(V2 + (n2 * 16 + lanen) * 104 + ks * 32 + quad * 8);
      o2[n2] = __builtin_amdgcn_mfma_f32_16x16x32_bf16(pfr, vfr, o2[n2], 0, 0, 0);
    }
  }
  #pragma unroll
  for (int n2 = 0; n2 < 2; ++n2) {
    int col = hh * 32 + n2 * 16 + lanen;
    #pragma unroll
    for (int r = 0; r < 4; ++r)
      out[((size_t)w * 72 + mo + quad * 4 + r) * 192 + col] = o2[n2][r];
  }
}

// ---------------- kernel C: out = po @ w_out + b_out (in-place on d_out) ----------------
__global__ __launch_bounds__(512)
void outproj_kernel(const unsigned char* __restrict__ ws, const float* __restrict__ bout,
                    float* __restrict__ out) {
  __shared__ unsigned short Ax[72 * AXS];   // 56,448 B static -> 2 blocks/CU, 16 waves
  const int w = blockIdx.x, tid = threadIdx.x;
  const int lane = tid & 63, ty = tid >> 6;
  const int lanen = lane & 15, quad = lane >> 4;
  const unsigned short* Bo = (const unsigned short*)(ws + WOUT_OFF);
  float* rows = out + (size_t)w * (72 * 192);

  for (int i = tid; i < 3456; i += 512) {   // stage po(f32) split into LDS
    int r = i / 48, c4 = i % 48;
    float4 v = *(const float4*)(rows + r * 192 + c4 * 4);
    unsigned short h0 = f2bf(v.x), h1 = f2bf(v.y), h2 = f2bf(v.z), h3 = f2bf(v.w);
    ushort4 hv; hv.x = h0; hv.y = h1; hv.z = h2; hv.w = h3;
    ushort4 lv;
    lv.x = f2bf(v.x - bf2f(h0)); lv.y = f2bf(v.y - bf2f(h1));
    lv.z = f2bf(v.z - bf2f(h2)); lv.w = f2bf(v.w - bf2f(h3));
    *(ushort4*)(Ax + r * AXS + c4 * 4) = hv;
    *(ushort4*)(Ax + r * AXS + 192 + c4 * 4) = lv;
  }
  __syncthreads();

  const int mg = ty >> 2, nq = ty & 3;      // 2 m-groups x 4 n-quarters (12 n-tiles)
  const int ngb = nq * 3;
  if (mg == 0) {
    f32x4 acc[3][3];
    split_gemm<3>(Ax, Bo, ngb, 0, lanen, quad, acc);
    #pragma unroll 1
    for (int nt = 0; nt < 3; ++nt) {
      const int n16 = (ngb + nt) * 16;
      const float bias = bout[n16 + lanen];
      #pragma unroll
      for (int mi = 0; mi < 3; ++mi) {
        const int mo = moffv(mi);
        #pragma unroll
        for (int r = 0; r < 4; ++r)
          rows[(size_t)(mo + quad * 4 + r) * 192 + n16 + lanen] = acc[nt][mi][r] + bias;
      }
    }
  } else {
    f32x4 acc[3][2];
    split_gemm<2>(Ax, Bo, ngb, 3, lanen, quad, acc);
    #pragma unroll 1
    for (int nt = 0; nt < 3; ++nt) {
      const int n16 = (ngb + nt) * 16;
      const float bias = bout[n16 + lanen];
      #pragma unroll
      for (int mi = 0; mi < 2; ++mi) {
        const int mo = moffv(3 + mi);
        #pragma unroll
        for (int r = 0; r < 4; ++r)
          rows[(size_t)(mo + quad * 4 + r) * 192 + n16 + lanen] = acc[nt][mi][r] + bias;
      }
    }
  }
}

extern "C" void kernel_launch(void* const* d_in, const int* in_sizes, int n_in,
                              void* d_out, int out_size, void* d_ws, size_t ws_size,
                              hipStream_t stream) {
  const float* x    = (const float*)d_in[0];
  const float* mask = (const float*)d_in[1];
  const float* wqkv = (const float*)d_in[2];
  const float* bqkv = (const float*)d_in[3];
  const float* wout = (const float*)d_in[4];
  const float* bout = (const float*)d_in[5];
  const float* btab = (const float*)d_in[6];
  float* out = (float*)d_out;
  unsigned char* ws = (unsigned char*)d_ws;
  const int nwindows = in_sizes[0] / (72 * 192);   // 1860
  // needs ws_size >= ~155 MB (weight tables + q/k/v bf16 staging)

  prep_kernel<<<dim3(1155), dim3(256), 0, stream>>>(wqkv, bqkv, wout, ws);
  qkv_kernel<<<dim3(nwindows), dim3(512), 0, stream>>>(x, ws);
  attn_core<<<dim3(nwindows * 6), dim3(320), 0, stream>>>(mask, btab, ws, out);
  outproj_kernel<<<dim3(nwindows), dim3(512), 0, stream>>>(ws, bout, out);
}